// Round 1
// 343.790 us; speedup vs baseline: 1.1189x; 1.1189x over previous
//
#include <hip/hip_runtime.h>

#define NCH   96
#define RF    25
#define HALF  12
#define HW    55
#define PLANE (HW * HW)   // 3025
#define CAP   32          // max compact taps per channel; dense fallback beyond
#define MAXA  6           // max active channels on the LDS fast path
#define SROWS 38          // 14 output rows + 24 halo
#define LDSW  56          // padded row width in LDS
#define SPLANE (SROWS * HW)   // 2090 staged pixels per active channel
#define LATP  (14 * HW)       // 770 lateral pixels per active channel (max)

// d_ws layout:
//   int   counts[NCH]            @ 0        (384 B)
//   int   tap_off[NCH][CAP]      @ 384      (12288 B)  packed (dy<<8)|dx
//   float tap_w [NCH][CAP]       @ 12672    (12288 B)
//   int   meta[1+MAXA]           @ 24960    (n_active, active_ch[]; 999 if fallback)
#define WS_META_OFF (NCH * 4 + NCH * CAP * 4 * 2)

// Single prep launch: 16 waves scan 6 channels each (ballot-compaction),
// then thread 0 builds the active-channel meta list.
__global__ __launch_bounds__(1024) void prep_all(
        const float* __restrict__ kern, int* __restrict__ counts,
        int* __restrict__ tap_off, float* __restrict__ tap_w,
        int* __restrict__ meta) {
    __shared__ int scnt[NCH];
    const int wave = threadIdx.x >> 6;
    const int lane = threadIdx.x & 63;
    for (int c = wave; c < NCH; c += 16) {
        const float* kc = kern + c * (RF * RF);
        int base = 0;
        for (int seg = 0; seg < RF * RF; seg += 64) {
            const int i = seg + lane;
            const float w = (i < RF * RF) ? kc[i] : 0.0f;
            const unsigned long long m = __ballot(w != 0.0f);
            const int pos = base + __popcll(m & ((1ull << lane) - 1ull));
            if (w != 0.0f && pos < CAP) {
                const int dy = i / RF, dx = i - dy * RF;
                tap_off[c * CAP + pos] = (dy << 8) | dx;
                tap_w[c * CAP + pos]   = w;
            }
            base += __popcll(m);
        }
        if (lane == 0) { counts[c] = base; scnt[c] = base; }
    }
    __syncthreads();
    if (threadIdx.x == 0) {
        int na = 0;
        bool fallback = false;
        for (int ch = 0; ch < NCH; ++ch) {
            if (scnt[ch] > 0) {
                if (scnt[ch] > CAP) fallback = true;
                if (na < MAXA) meta[1 + na] = ch;
                ++na;
            }
        }
        if (na > MAXA) fallback = true;
        meta[0] = fallback ? 999 : na;
        for (int a = (na > MAXA ? 0 : na); a < MAXA; ++a) meta[1 + a] = 0;
    }
}

// Block = quarter-image (rows q*14 .. q*14+13, last block 13 rows), 1024 thr.
// Grid = 512, swizzled: the 4 sibling blocks of image n land on XCD n%8,
// adjacent in dispatch order -> staged lines L2-shared with tight timing.
//
// V2 structure: single-write streaming.
//   phase A : gather active channels (center+halo, all 38 rows) -> LDS sh
//   phase C1: dense conv (all lanes) -> LDS lat[6][770]
//   phase B : ONE coalesced float4 stream: v = x; v[active] += lat; out = v
// No partial-line overwrites -> no HBM read-modify-write traffic.
__global__ __launch_bounds__(1024, 8) void contour_tile(
        const float* __restrict__ x, const float* __restrict__ kern,
        const int* __restrict__ counts, const int* __restrict__ tap_off,
        const float* __restrict__ tap_w, const int* __restrict__ meta,
        float* __restrict__ out) {
    __shared__ float sh[MAXA][SROWS][LDSW];   // 51,072 B
    __shared__ float latf[MAXA * LATP];       // 18,480 B
    __shared__ float tw[MAXA][CAP];
    __shared__ int   toff[MAXA][CAP];
    __shared__ int   tcnt[MAXA];
    __shared__ int   chA[MAXA];
    __shared__ signed char c2a[NCH];

    const int tid  = threadIdx.x;
    const int b    = blockIdx.x;
    const int xcd  = b & 7;
    const int s    = b >> 3;          // 0..63
    const int n    = xcd + ((s >> 2) << 3);   // image 0..127
    const int q    = s & 3;           // quarter 0..3
    const int y0   = q * 14;
    const int rows = (q < 3) ? 14 : 13;
    const int npx  = rows * HW;

    const float* xn = x   + (size_t)n * (PLANE * NCH);
    float*       on = out + (size_t)n * (PLANE * NCH);

    const int na = meta[0];
    const bool fast = (na <= MAXA);

    // ---- phase 0: tap/meta tables into LDS ----
    if (tid < NCH) c2a[tid] = -1;
    __syncthreads();
    if (fast) {
        if (tid < MAXA) {
            const int c = (tid < na) ? meta[1 + tid] : -1;
            chA[tid]  = c;
            tcnt[tid] = (c >= 0) ? counts[c] : 0;
        }
        if (tid < na) c2a[meta[1 + tid]] = (signed char)tid;
        if (tid >= 64 && tid < 64 + MAXA * CAP) {
            const int a = (tid - 64) / CAP, t = (tid - 64) % CAP;
            const int c = (a < na) ? meta[1 + a] : 0;
            toff[a][t] = tap_off[c * CAP + t];
            tw[a][t]   = tap_w[c * CAP + t];
        }
    }
    __syncthreads();

    if (fast) {
        // ---- phase A: gather active-channel tile (center + halo) into LDS ----
        // Scattered 4B loads; lines re-used by the phase-B stream land in L2/L3,
        // and x (149 MB) fits entirely in the 256 MB L3, so no extra HBM fetch.
        const int totA = na * SPLANE;
        for (int idx = tid; idx < totA; idx += 1024) {
            const int a   = idx / SPLANE;          // const-divisor magic mul
            const int rem = idx - a * SPLANE;
            const int sr  = rem / HW;
            const int col = rem - sr * HW;
            const int gy  = y0 - HALF + sr;
            float v = 0.0f;
            if ((unsigned)gy < (unsigned)HW)
                v = xn[(size_t)(gy * HW + col) * NCH + chA[a]];
            sh[a][sr][col] = v;
        }
        __syncthreads();

        // ---- phase C1: dense conv, all lanes busy, result -> lat ----
        // (for q==3 indices p in [715,770) compute harmless junk from the
        //  zero-filled sh rows; phase B never reads them)
        const int totC = na * LATP;
        for (int idx = tid; idx < totC; idx += 1024) {
            const int a   = idx / LATP;
            const int p   = idx - a * LATP;
            const int r   = p / HW;
            const int col = p - r * HW;
            const int cnt = tcnt[a];
            float acc = 0.0f;
            for (int t = 0; t < cnt; ++t) {
                const int off = toff[a][t];
                const float w = tw[a][t];
                const int dy = off >> 8, dx = off & 255;
                const int xx = col + dx - HALF;
                const bool ok = (unsigned)xx < (unsigned)HW;
                const int  xc = min(max(xx, 0), HW - 1);
                const float vv = sh[a][r + dy][xc];
                acc += ok ? w * vv : 0.0f;
            }
            latf[idx] = acc;
        }
        __syncthreads();

        // ---- phase B: single coalesced stream, fused add, single write ----
        // thread -> fixed channel-group g = tid%24; 1008 threads cover all
        // (pixel, group) float4s with contiguous wave addressing.
        if (tid < 1008) {
            const int g     = tid % 24;
            const int pslot = tid / 24;            // 0..41
            const int a0 = c2a[g * 4 + 0];
            const int a1 = c2a[g * 4 + 1];
            const int a2 = c2a[g * 4 + 2];
            const int a3 = c2a[g * 4 + 3];
            const bool anyact = (a0 >= 0) | (a1 >= 0) | (a2 >= 0) | (a3 >= 0);
            const float4* xs = (const float4*)(xn + (size_t)y0 * HW * NCH);
            float4*       os = (float4*)      (on + (size_t)y0 * HW * NCH);
            #pragma unroll 2
            for (int p = pslot; p < npx; p += 42) {
                const int idx = p * 24 + g;        // contiguous across the wave
                float4 v = xs[idx];
                if (anyact) {
                    if (a0 >= 0) v.x += latf[a0 * LATP + p];
                    if (a1 >= 0) v.y += latf[a1 * LATP + p];
                    if (a2 >= 0) v.z += latf[a2 * LATP + p];
                    if (a3 >= 0) v.w += latf[a3 * LATP + p];
                }
                os[idx] = v;                        // full-coverage, no RMW
            }
        }
    } else {
        // ---- generic fallback (never taken for the reference mask) ----
        for (int idx = tid; idx < npx * (NCH / 4); idx += 1024) {
            const int g   = idx % (NCH / 4);
            const int pix = idx / (NCH / 4);
            const int r   = pix / HW;
            const int col = pix - r * HW;
            const int py  = y0 + r;
            const size_t pbase = (size_t)(py * HW + col) * NCH;
            const float4 xv = *(const float4*)(xn + pbase + g * 4);
            float acc[4] = {xv.x, xv.y, xv.z, xv.w};
            for (int kk = 0; kk < 4; ++kk) {
                const int c = g * 4 + kk;
                const int cnt = counts[c];
                if (cnt == 0) continue;
                float aa = 0.0f;
                if (cnt <= CAP) {
                    for (int t = 0; t < cnt; ++t) {
                        const int off = tap_off[c * CAP + t];
                        const float w = tap_w[c * CAP + t];
                        const int dy = off >> 8, dx = off & 255;
                        const int yy = py + dy - HALF;
                        const int xx = col + dx - HALF;
                        if ((unsigned)yy < (unsigned)HW && (unsigned)xx < (unsigned)HW)
                            aa += w * xn[(size_t)(yy * HW + xx) * NCH + c];
                    }
                } else {
                    for (int dy = 0; dy < RF; ++dy)
                        for (int dx = 0; dx < RF; ++dx) {
                            const float w = kern[(c * RF + dy) * RF + dx];
                            if (w == 0.0f) continue;
                            const int yy = py + dy - HALF;
                            const int xx = col + dx - HALF;
                            if ((unsigned)yy < (unsigned)HW && (unsigned)xx < (unsigned)HW)
                                aa += w * xn[(size_t)(yy * HW + xx) * NCH + c];
                        }
                }
                acc[kk] += aa;
            }
            *(float4*)(on + pbase + g * 4) = make_float4(acc[0], acc[1], acc[2], acc[3]);
        }
    }
}

extern "C" void kernel_launch(void* const* d_in, const int* in_sizes, int n_in,
                              void* d_out, int out_size, void* d_ws, size_t ws_size,
                              hipStream_t stream) {
    const float* x    = (const float*)d_in[0];
    const float* kern = (const float*)d_in[1];
    float* out = (float*)d_out;

    int*   counts  = (int*)d_ws;
    int*   tap_off = (int*)((char*)d_ws + NCH * 4);
    float* tap_w   = (float*)((char*)d_ws + NCH * 4 + NCH * CAP * 4);
    int*   meta    = (int*)((char*)d_ws + WS_META_OFF);

    prep_all<<<1, 1024, 0, stream>>>(kern, counts, tap_off, tap_w, meta);

    // 128 images x 4 quarter-stripes, XCD-swizzled (siblings share an XCD)
    contour_tile<<<512, 1024, 0, stream>>>(x, kern, counts, tap_off, tap_w, meta, out);
}